// Round 1
// baseline (437.742 us; speedup 1.0000x reference)
//
#include <hip/hip_runtime.h>
#include <math.h>

// Soft decision-tree ensemble forward.
// x: [B=1024, T=16, D=10, W=512] fp32 flat. out: [B, T] fp32.
// One wave (64 lanes) per (b,t). Lane j owns elements [8j, 8j+8) of each row.

#define NUM_TREES 16
#define DEPTH     10
#define WIDTH     512
#define BATCH     1024

__device__ __forceinline__ float sigmoidf_fast(float x) {
    // sigmoid(x) = 1 / (1 + exp(-x)); __expf -> v_exp_f32, __fdividef -> fast rcp path.
    return __fdividef(1.0f, 1.0f + __expf(-x));
}

__global__ __launch_bounds__(256) void ndt_kernel(const float* __restrict__ x,
                                                  float* __restrict__ out) {
    const int wave_id = (blockIdx.x * blockDim.x + threadIdx.x) >> 6; // global wave = (b,t)
    const int lane = threadIdx.x & 63;
    const int b = wave_id >> 4;   // / NUM_TREES
    const int t = wave_id & 15;   // % NUM_TREES

    const float* base = x + (size_t)b * (NUM_TREES * DEPTH * WIDTH)
                          + (size_t)t * (DEPTH * WIDTH);
    const int e0 = lane * 8; // first element of this lane in each 512-row

    // ---- Load all 10 rows, 8 floats per lane (2x float4), 20 loads in flight ----
    float4 r[DEPTH][2];
#pragma unroll
    for (int i = 0; i < DEPTH; ++i) {
        const float4* p = (const float4*)(base + i * WIDTH + e0);
        r[i][0] = p[0];
        r[i][1] = p[1];
    }

    // ---- Level 9 (leaf sigmoids): v[n] for this lane's 8 leaves ----
    float v[8];
    {
        const float* q = (const float*)&r[9][0];
#pragma unroll
        for (int k = 0; k < 8; ++k) v[k] = sigmoidf_fast(q[k]);
    }
    // ---- Level 8: width-2 means, fold 8 -> 4 ----
    {
        const float* q = (const float*)&r[8][0];
#pragma unroll
        for (int k = 0; k < 4; ++k) {
            float d = 0.5f * (sigmoidf_fast(q[2 * k]) + sigmoidf_fast(q[2 * k + 1]));
            v[k] = (1.0f - d) * v[2 * k] + d * v[2 * k + 1];
        }
    }
    // ---- Level 7: width-4 means, fold 4 -> 2 ----
    {
        const float* q = (const float*)&r[7][0];
#pragma unroll
        for (int k = 0; k < 2; ++k) {
            float d = 0.25f * (sigmoidf_fast(q[4 * k])     + sigmoidf_fast(q[4 * k + 1]) +
                               sigmoidf_fast(q[4 * k + 2]) + sigmoidf_fast(q[4 * k + 3]));
            v[k] = (1.0f - d) * v[2 * k] + d * v[2 * k + 1];
        }
    }
    // ---- Level 6: width-8 mean (whole lane), fold 2 -> 1 ----
    float vv;
    {
        const float* q = (const float*)&r[6][0];
        float s = 0.0f;
#pragma unroll
        for (int k = 0; k < 8; ++k) s += sigmoidf_fast(q[k]);
        const float d = s * 0.125f;
        vv = (1.0f - d) * v[0] + d * v[1];
    }
    // ---- Levels 0..5: per-lane partial sums of sigmoids ----
    float S[6];
#pragma unroll
    for (int i = 0; i < 6; ++i) {
        const float* q = (const float*)&r[i][0];
        float s = 0.0f;
#pragma unroll
        for (int k = 0; k < 8; ++k) s += sigmoidf_fast(q[k]);
        S[i] = s;
    }

    // ---- Butterfly fold, levels 5 down to 0 ----
    // At step s (h = 1<<s): fold level lvl = 5-s, segment width = 16<<s (power of 2).
#pragma unroll
    for (int step = 0; step < 6; ++step) {
        const int h = 1 << step;
        const int lvl = 5 - step;
        // Accumulate remaining row sums across distance h; after this,
        // S[lvl] holds the full segment sum over 2h lanes (= width 16<<step elems).
#pragma unroll
        for (int i2 = 0; i2 <= lvl; ++i2) S[i2] += __shfl_xor(S[i2], h, 64);

        const float d = S[lvl] * (1.0f / (float)(16 << step)); // exact pow2 recip
        const float vo = __shfl_xor(vv, h, 64);
        const bool upper = ((lane >> step) & 1) != 0;
        const float v_even = upper ? vo : vv;
        const float v_odd  = upper ? vv : vo;
        vv = (1.0f - d) * v_even + d * v_odd;
    }

    if (lane == 0) out[wave_id] = vv;
}

extern "C" void kernel_launch(void* const* d_in, const int* in_sizes, int n_in,
                              void* d_out, int out_size, void* d_ws, size_t ws_size,
                              hipStream_t stream) {
    const float* x = (const float*)d_in[0];
    float* out = (float*)d_out;
    // 16384 waves (one per (b,t)), 4 waves/block -> 4096 blocks of 256.
    const int total_waves = BATCH * NUM_TREES;
    const int block = 256;
    const int grid = total_waves / (block / 64);
    ndt_kernel<<<grid, block, 0, stream>>>(x, out);
}

// Round 2
// 437.162 us; speedup vs baseline: 1.0013x; 1.0013x over previous
//
#include <hip/hip_runtime.h>
#include <math.h>

// Soft decision-tree ensemble forward.
// x: [B=1024, T=16, D=10, W=512] fp32 flat. out: [B, T] fp32.
// One wave (64 lanes) per (b,t). Lane j owns elements [8j, 8j+8) of each row.
//
// Register-streaming version: rows 0..5 (sum-only levels) are loaded and
// reduced to per-lane scalars S[0..5] BEFORE rows 6..9 are loaded, capping
// peak live data registers at ~12 float4 (vs 20) -> ~6 waves/SIMD occupancy.

#define NUM_TREES 16
#define DEPTH     10
#define WIDTH     512
#define BATCH     1024

__device__ __forceinline__ float sigmoidf_fast(float x) {
    return __fdividef(1.0f, 1.0f + __expf(-x));
}

__device__ __forceinline__ float sum8_sigmoid(const float4& a, const float4& b) {
    return sigmoidf_fast(a.x) + sigmoidf_fast(a.y) + sigmoidf_fast(a.z) + sigmoidf_fast(a.w) +
           sigmoidf_fast(b.x) + sigmoidf_fast(b.y) + sigmoidf_fast(b.z) + sigmoidf_fast(b.w);
}

__global__ __launch_bounds__(256) void ndt_kernel(const float* __restrict__ x,
                                                  float* __restrict__ out) {
    const int wave_id = (blockIdx.x * blockDim.x + threadIdx.x) >> 6; // (b,t)
    const int lane = threadIdx.x & 63;
    const int b = wave_id >> 4;
    const int t = wave_id & 15;

    const float* base = x + (size_t)b * (NUM_TREES * DEPTH * WIDTH)
                          + (size_t)t * (DEPTH * WIDTH);
    const int e0 = lane * 8;

    // ---- Phase 1: rows 0..5 -> per-lane sigmoid sums S[i] (12 float4 in flight) ----
    float4 rs[6][2];
#pragma unroll
    for (int i = 0; i < 6; ++i) {
        const float4* p = (const float4*)(base + i * WIDTH + e0);
        rs[i][0] = p[0];
        rs[i][1] = p[1];
    }
    float S[6];
#pragma unroll
    for (int i = 0; i < 6; ++i) S[i] = sum8_sigmoid(rs[i][0], rs[i][1]);

    // ---- Phase 2: rows 6..9 (leaf-fold levels), registers reused from rs ----
    float4 rv[4][2];
#pragma unroll
    for (int i = 0; i < 4; ++i) {
        const float4* p = (const float4*)(base + (6 + i) * WIDTH + e0);
        rv[i][0] = p[0];
        rv[i][1] = p[1];
    }

    // Level 9 (leaf sigmoids): v[0..7]
    float v[8];
    {
        const float* q = (const float*)&rv[3][0];
#pragma unroll
        for (int k = 0; k < 8; ++k) v[k] = sigmoidf_fast(q[k]);
    }
    // Level 8: width-2 means, fold 8 -> 4
    {
        const float* q = (const float*)&rv[2][0];
#pragma unroll
        for (int k = 0; k < 4; ++k) {
            float d = 0.5f * (sigmoidf_fast(q[2 * k]) + sigmoidf_fast(q[2 * k + 1]));
            v[k] = (1.0f - d) * v[2 * k] + d * v[2 * k + 1];
        }
    }
    // Level 7: width-4 means, fold 4 -> 2
    {
        const float* q = (const float*)&rv[1][0];
#pragma unroll
        for (int k = 0; k < 2; ++k) {
            float d = 0.25f * (sigmoidf_fast(q[4 * k])     + sigmoidf_fast(q[4 * k + 1]) +
                               sigmoidf_fast(q[4 * k + 2]) + sigmoidf_fast(q[4 * k + 3]));
            v[k] = (1.0f - d) * v[2 * k] + d * v[2 * k + 1];
        }
    }
    // Level 6: width-8 mean (whole lane), fold 2 -> 1
    float vv;
    {
        const float d = sum8_sigmoid(rv[0][0], rv[0][1]) * 0.125f;
        vv = (1.0f - d) * v[0] + d * v[1];
    }

    // ---- Butterfly fold, levels 5 down to 0 ----
#pragma unroll
    for (int step = 0; step < 6; ++step) {
        const int h = 1 << step;
        const int lvl = 5 - step;
#pragma unroll
        for (int i2 = 0; i2 <= lvl; ++i2) S[i2] += __shfl_xor(S[i2], h, 64);

        const float d = S[lvl] * (1.0f / (float)(16 << step)); // exact pow2 recip
        const float vo = __shfl_xor(vv, h, 64);
        const bool upper = ((lane >> step) & 1) != 0;
        const float v_even = upper ? vo : vv;
        const float v_odd  = upper ? vv : vo;
        vv = (1.0f - d) * v_even + d * v_odd;
    }

    if (lane == 0) out[wave_id] = vv;
}

extern "C" void kernel_launch(void* const* d_in, const int* in_sizes, int n_in,
                              void* d_out, int out_size, void* d_ws, size_t ws_size,
                              hipStream_t stream) {
    const float* x = (const float*)d_in[0];
    float* out = (float*)d_out;
    const int total_waves = BATCH * NUM_TREES; // 16384
    const int block = 256;
    const int grid = total_waves / (block / 64); // 4096
    ndt_kernel<<<grid, block, 0, stream>>>(x, out);
}